// Round 2
// baseline (310.072 us; speedup 1.0000x reference)
//
#include <hip/hip_runtime.h>
#include <stdint.h>

typedef __attribute__((ext_vector_type(8))) __bf16 bf16x8;
typedef __attribute__((ext_vector_type(4))) float f32x4;
typedef __attribute__((ext_vector_type(4))) float fl4;
typedef __attribute__((ext_vector_type(8))) unsigned short us8;
typedef __attribute__((ext_vector_type(4))) unsigned short us4;

__device__ __forceinline__ unsigned short f2bf(float f) {
  union { float f; unsigned int u; } v;
  v.f = f;
  unsigned int r = v.u + 0x7FFFu + ((v.u >> 16) & 1u);
  return (unsigned short)(r >> 16);
}

#define GLOAD_LDS16(g, l)                                                   \
  __builtin_amdgcn_global_load_lds(                                         \
      (const __attribute__((address_space(1))) void*)(g),                   \
      (__attribute__((address_space(3))) void*)(l), 16, 0, 0)

#define MEMFENCE asm volatile("" ::: "memory")

// ---------------- fp32 -> bf16 conversion ----------------
__global__ void f32_to_bf16_kernel(const float* __restrict__ in,
                                   unsigned short* __restrict__ out, int n) {
  int i = (blockIdx.x * blockDim.x + threadIdx.x) * 4;
  if (i + 3 < n) {
    fl4 v = *(const fl4*)(in + i);
    us4 o;
    o[0] = f2bf(v[0]);
    o[1] = f2bf(v[1]);
    o[2] = f2bf(v[2]);
    o[3] = f2bf(v[3]);
    *(us4*)(out + i) = o;
  }
}

// ---------------- 256x256 8-wave counted-vmcnt bf16 NT GEMM ----------------
// C = A(MxK) * B(NxK)^T + bias.  A,B row-major K-contiguous bf16.
// BM=BN=256, BK=64, 512 threads (8 waves, 2M x 4N), per-wave C = 128x64.
// LDS 128 KB: A/B double-buffered [2][256][64] bf16, T2 swizzle
// byte ^= ((row&7)<<4) applied via inverse-swizzled global source (linear
// global_load_lds dest) + swizzled ds_read.  Counted vmcnt(4) at tile end.
template <bool OUT_BF16>
__global__ __launch_bounds__(512, 2) void gemm256_kernel(
    const unsigned short* __restrict__ A, const unsigned short* __restrict__ B,
    const float* __restrict__ bias, void* __restrict__ Cout, int M, int N,
    int K) {
  __shared__ __align__(16) unsigned short lds[65536];  // 128 KB
  char* ldsA = (char*)lds;          // [2][256][64] bf16 : 2*32768 B
  char* ldsB = (char*)lds + 65536;  // [2][256][64] bf16

  const int tid = threadIdx.x;
  const int lane = tid & 63;
  const int wid = tid >> 6;
  const int wm = wid >> 2;  // 0..1
  const int wn = wid & 3;   // 0..3
  const int lr = lane & 15;
  const int lg = lane >> 4;  // 0..3

  // XCD-bijective block remap (gridDim.x % 8 == 0 by construction)
  const int nwg = gridDim.x;
  const int cpx = nwg >> 3;
  const int bid = blockIdx.x;
  const int id2 = (bid & 7) * cpx + (bid >> 3);
  const int MT = M >> 8;
  const int bm = (id2 % MT) << 8;
  const int bn = (id2 / MT) << 8;

  const int nkt = K >> 6;  // K-tiles of 64 (assumed >= 2)

  // ---- staging constants: thread t covers LDS bytes [t*16, t*16+16) of each
  // 8 KB quarter (64 rows); source col pre-swizzled so LDS holds
  // data[row][c' ^ ((row&7)<<4)] at linear [row][c'].
  const int srow = tid >> 3;  // 0..63 (row within quarter)
  const int scolb = (((tid & 7) << 4) ^ ((srow & 7) << 4));
  const char* Ab = (const char*)A;
  const char* Bb = (const char*)B;

#define STAGE_A(kt2, q)                                                        \
  GLOAD_LDS16(Ab + ((size_t)(bm + (q)*64 + srow) * K + (kt2)*64) * 2 + scolb,  \
              ldsA + (((kt2)&1) * 32768) + (q)*8192 + tid * 16)
#define STAGE_B(kt2, q)                                                        \
  GLOAD_LDS16(Bb + ((size_t)(bn + (q)*64 + srow) * K + (kt2)*64) * 2 + scolb,  \
              ldsB + (((kt2)&1) * 32768) + (q)*8192 + tid * 16)

  // ---- fragment-read constants (swizzled ds_read)
  const int swzb = (lr & 7) << 4;
  const int lkb = lg << 4;              // 0,16,32,48 bytes within K=32 group
  const int ck0 = (0 + lkb) ^ swzb;     // kk=0 col byte
  const int ck1 = (64 + lkb) ^ swzb;    // kk=1 col byte

  f32x4 acc[8][4];
#pragma unroll
  for (int m = 0; m < 8; ++m)
#pragma unroll
    for (int n = 0; n < 4; ++n) acc[m][n] = (f32x4){0.f, 0.f, 0.f, 0.f};

  // ---- prologue: full tile 0 (A+B) + A of tile 1 in flight
#pragma unroll
  for (int q = 0; q < 4; ++q) STAGE_A(0, q);
#pragma unroll
  for (int q = 0; q < 4; ++q) STAGE_B(0, q);
#pragma unroll
  for (int q = 0; q < 4; ++q) STAGE_A(1, q);
  asm volatile("s_waitcnt vmcnt(4)" ::: "memory");
  __builtin_amdgcn_s_barrier();
  MEMFENCE;

  for (int kt = 0; kt < nkt; ++kt) {
    const int p = kt & 1;
    const char* rA = ldsA + p * 32768;
    const char* rB = ldsB + p * 32768;
    const int arow = (wm * 128 + lr) * 128;  // byte row base for A frags
    const int brow = (wn * 64 + lr) * 128;   // byte row base for B frags

    bf16x8 a0[4][2], a1[4][2], b0[2][2], b1[2][2];

    // ===== phase 1: read A m0-3 + B n0-1; stage B(kt+1) Q0,Q1; MFMA q1
#pragma unroll
    for (int m = 0; m < 4; ++m) {
      a0[m][0] = *(const bf16x8*)(rA + arow + m * 2048 + ck0);
      a0[m][1] = *(const bf16x8*)(rA + arow + m * 2048 + ck1);
    }
#pragma unroll
    for (int n = 0; n < 2; ++n) {
      b0[n][0] = *(const bf16x8*)(rB + brow + n * 2048 + ck0);
      b0[n][1] = *(const bf16x8*)(rB + brow + n * 2048 + ck1);
    }
    if (kt + 1 < nkt) { STAGE_B(kt + 1, 0); STAGE_B(kt + 1, 1); }
    MEMFENCE;
    __builtin_amdgcn_s_barrier();
    MEMFENCE;
    __builtin_amdgcn_s_setprio(1);
#pragma unroll
    for (int m = 0; m < 4; ++m)
#pragma unroll
      for (int n = 0; n < 2; ++n) {
        acc[m][n] = __builtin_amdgcn_mfma_f32_16x16x32_bf16(a0[m][0], b0[n][0], acc[m][n], 0, 0, 0);
        acc[m][n] = __builtin_amdgcn_mfma_f32_16x16x32_bf16(a0[m][1], b0[n][1], acc[m][n], 0, 0, 0);
      }
    __builtin_amdgcn_s_setprio(0);
    MEMFENCE;
    __builtin_amdgcn_s_barrier();
    MEMFENCE;

    // ===== phase 2: read B n2-3; stage B(kt+1) Q2,Q3 + A(kt+2) Q0; MFMA q2
#pragma unroll
    for (int n = 0; n < 2; ++n) {
      b1[n][0] = *(const bf16x8*)(rB + brow + (n + 2) * 2048 + ck0);
      b1[n][1] = *(const bf16x8*)(rB + brow + (n + 2) * 2048 + ck1);
    }
    if (kt + 1 < nkt) { STAGE_B(kt + 1, 2); STAGE_B(kt + 1, 3); }
    if (kt + 2 < nkt) { STAGE_A(kt + 2, 0); }
    MEMFENCE;
    __builtin_amdgcn_s_barrier();
    MEMFENCE;
    __builtin_amdgcn_s_setprio(1);
#pragma unroll
    for (int m = 0; m < 4; ++m)
#pragma unroll
      for (int n = 0; n < 2; ++n) {
        acc[m][n + 2] = __builtin_amdgcn_mfma_f32_16x16x32_bf16(a0[m][0], b1[n][0], acc[m][n + 2], 0, 0, 0);
        acc[m][n + 2] = __builtin_amdgcn_mfma_f32_16x16x32_bf16(a0[m][1], b1[n][1], acc[m][n + 2], 0, 0, 0);
      }
    __builtin_amdgcn_s_setprio(0);
    MEMFENCE;
    __builtin_amdgcn_s_barrier();
    MEMFENCE;

    // ===== phase 3: read A m4-7; stage A(kt+2) Q2; MFMA q3
#pragma unroll
    for (int m = 0; m < 4; ++m) {
      a1[m][0] = *(const bf16x8*)(rA + arow + (m + 4) * 2048 + ck0);
      a1[m][1] = *(const bf16x8*)(rA + arow + (m + 4) * 2048 + ck1);
    }
    if (kt + 2 < nkt) { STAGE_A(kt + 2, 2); }
    MEMFENCE;
    __builtin_amdgcn_s_barrier();
    MEMFENCE;
    __builtin_amdgcn_s_setprio(1);
#pragma unroll
    for (int m = 0; m < 4; ++m)
#pragma unroll
      for (int n = 0; n < 2; ++n) {
        acc[m + 4][n] = __builtin_amdgcn_mfma_f32_16x16x32_bf16(a1[m][0], b0[n][0], acc[m + 4][n], 0, 0, 0);
        acc[m + 4][n] = __builtin_amdgcn_mfma_f32_16x16x32_bf16(a1[m][1], b0[n][1], acc[m + 4][n], 0, 0, 0);
      }
    __builtin_amdgcn_s_setprio(0);
    MEMFENCE;
    __builtin_amdgcn_s_barrier();
    MEMFENCE;

    // ===== phase 4: stage A(kt+2) Q1,Q3; MFMA q4; counted vmcnt
    if (kt + 2 < nkt) { STAGE_A(kt + 2, 1); STAGE_A(kt + 2, 3); }
    MEMFENCE;
    __builtin_amdgcn_s_barrier();
    MEMFENCE;
    __builtin_amdgcn_s_setprio(1);
#pragma unroll
    for (int m = 0; m < 4; ++m)
#pragma unroll
      for (int n = 0; n < 2; ++n) {
        acc[m + 4][n + 2] = __builtin_amdgcn_mfma_f32_16x16x32_bf16(a1[m][0], b1[n][0], acc[m + 4][n + 2], 0, 0, 0);
        acc[m + 4][n + 2] = __builtin_amdgcn_mfma_f32_16x16x32_bf16(a1[m][1], b1[n][1], acc[m + 4][n + 2], 0, 0, 0);
      }
    __builtin_amdgcn_s_setprio(0);
    if (kt + 2 < nkt) {
      asm volatile("s_waitcnt vmcnt(4)" ::: "memory");  // tile kt+1 landed
    } else {
      asm volatile("s_waitcnt vmcnt(0)" ::: "memory");
    }
    __builtin_amdgcn_s_barrier();
    MEMFENCE;
  }

#undef STAGE_A
#undef STAGE_B

  // ---- epilogue
  const int crow0 = bm + wm * 128 + lg * 4;
  const int ccol0 = bn + wn * 64 + lr;
#pragma unroll
  for (int n = 0; n < 4; ++n) {
    const int col = ccol0 + n * 16;
    const float bv = bias[col];
#pragma unroll
    for (int m = 0; m < 8; ++m) {
#pragma unroll
      for (int j = 0; j < 4; ++j) {
        const int row = crow0 + m * 16 + j;
        const float val = acc[m][n][j] + bv;
        if (OUT_BF16)
          ((unsigned short*)Cout)[(size_t)row * N + col] = f2bf(val);
        else
          ((float*)Cout)[(size_t)row * N + col] = val;
      }
    }
  }
}

// ---------------- attention: one WG (4 waves) per (b, h) ----------------
__global__ __launch_bounds__(256, 2) void attn_kernel(
    const unsigned short* __restrict__ qkv, const float* __restrict__ abias,
    const float* __restrict__ mask, unsigned short* __restrict__ out) {
  __shared__ __align__(16) unsigned short lq[64 * 40];
  __shared__ __align__(16) unsigned short lk[64 * 40];
  __shared__ __align__(16) unsigned short lvT[32 * 72];
  __shared__ __align__(16) float ls[64 * 68];
  __shared__ __align__(16) unsigned short lp[64 * 72];

  const int blk = blockIdx.x;
  const int b = blk >> 4;
  const int h = blk & 15;
  const int tid = threadIdx.x;
  const int lane = tid & 63;
  const int wid = tid >> 6;
  const int lr = lane & 15;
  const int lk8 = (lane >> 4) * 8;

  {
    const int r = tid >> 2;
    const int d0 = (tid & 3) * 8;
    const size_t base = (size_t)(b * 64 + r) * 1536 + h * 32 + d0;
    us8 qv = *(const us8*)(qkv + base);
    us8 kv = *(const us8*)(qkv + base + 512);
    us8 vv = *(const us8*)(qkv + base + 1024);
    *(us8*)(lq + r * 40 + d0) = qv;
    *(us8*)(lk + r * 40 + d0) = kv;
#pragma unroll
    for (int i = 0; i < 8; ++i) lvT[(d0 + i) * 72 + r] = vv[i];
  }
  __syncthreads();

  f32x4 s[4];
  {
    bf16x8 aq = *(const bf16x8*)(lq + (wid * 16 + lr) * 40 + lk8);
#pragma unroll
    for (int n = 0; n < 4; ++n) {
      bf16x8 bk = *(const bf16x8*)(lk + (n * 16 + lr) * 40 + lk8);
      f32x4 z = {0.f, 0.f, 0.f, 0.f};
      s[n] = __builtin_amdgcn_mfma_f32_16x16x32_bf16(aq, bk, z, 0, 0, 0);
    }
  }
  const float scale = 0.17677669529663687f;
  const int sr0 = wid * 16 + (lane >> 4) * 4;
#pragma unroll
  for (int n = 0; n < 4; ++n) {
    const int col = n * 16 + lr;
#pragma unroll
    for (int j = 0; j < 4; ++j) {
      const int row = sr0 + j;
      ls[row * 68 + col] = s[n][j] * scale + abias[(h * 64 + row) * 64 + col] +
                           mask[((size_t)b * 64 + row) * 64 + col];
    }
  }
  __syncthreads();

  {
    const int r = tid >> 2;
    const int c0 = (tid & 3) * 16;
    float e[16];
#pragma unroll
    for (int i = 0; i < 16; ++i) e[i] = ls[r * 68 + c0 + i];
    float mx = e[0];
#pragma unroll
    for (int i = 1; i < 16; ++i) mx = fmaxf(mx, e[i]);
    mx = fmaxf(mx, __shfl_xor(mx, 1));
    mx = fmaxf(mx, __shfl_xor(mx, 2));
    float sum = 0.f;
#pragma unroll
    for (int i = 0; i < 16; ++i) {
      e[i] = __expf(e[i] - mx);
      sum += e[i];
    }
    sum += __shfl_xor(sum, 1);
    sum += __shfl_xor(sum, 2);
    const float inv = 1.f / sum;
#pragma unroll
    for (int i = 0; i < 16; ++i) lp[r * 72 + c0 + i] = f2bf(e[i] * inv);
  }
  __syncthreads();

  f32x4 o[2];
  o[0] = (f32x4){0.f, 0.f, 0.f, 0.f};
  o[1] = o[0];
#pragma unroll
  for (int kk = 0; kk < 2; ++kk) {
    bf16x8 pa = *(const bf16x8*)(lp + (wid * 16 + lr) * 72 + kk * 32 + lk8);
#pragma unroll
    for (int d = 0; d < 2; ++d) {
      bf16x8 vb = *(const bf16x8*)(lvT + (d * 16 + lr) * 72 + kk * 32 + lk8);
      o[d] = __builtin_amdgcn_mfma_f32_16x16x32_bf16(pa, vb, o[d], 0, 0, 0);
    }
  }
#pragma unroll
  for (int d = 0; d < 2; ++d) {
    const int col = h * 32 + d * 16 + lr;
#pragma unroll
    for (int j = 0; j < 4; ++j) {
      const int row = sr0 + j;
      out[(size_t)(b * 64 + row) * 512 + col] = f2bf(o[d][j]);
    }
  }
}

// ---------------- launch ----------------
extern "C" void kernel_launch(void* const* d_in, const int* in_sizes, int n_in,
                              void* d_out, int out_size, void* d_ws,
                              size_t ws_size, hipStream_t stream) {
  (void)in_sizes; (void)n_in; (void)out_size; (void)ws_size;
  const float* x = (const float*)d_in[0];
  const float* abias = (const float*)d_in[1];
  const float* mask = (const float*)d_in[2];
  const float* qkv_w = (const float*)d_in[3];
  const float* qkv_b = (const float*)d_in[4];
  const float* proj_w = (const float*)d_in[5];
  const float* proj_b = (const float*)d_in[6];

  char* ws = (char*)d_ws;
  unsigned short* ws_x = (unsigned short*)(ws);
  unsigned short* ws_qkv = (unsigned short*)(ws + 33554432);
  unsigned short* ws_wq = (unsigned short*)(ws + 134217728);
  unsigned short* ws_wp = (unsigned short*)(ws + 135790592);
  unsigned short* ws_att = ws_x;  // alias: x consumed by qkv GEMM before attn writes

  f32_to_bf16_kernel<<<16384, 256, 0, stream>>>(x, ws_x, 16777216);
  f32_to_bf16_kernel<<<768, 256, 0, stream>>>(qkv_w, ws_wq, 786432);
  f32_to_bf16_kernel<<<256, 256, 0, stream>>>(proj_w, ws_wp, 262144);

  gemm256_kernel<true><<<768, 512, 0, stream>>>(ws_x, ws_wq, qkv_b, ws_qkv,
                                                32768, 1536, 512);

  attn_kernel<<<8192, 256, 0, stream>>>(ws_qkv, abias, mask, ws_att);

  gemm256_kernel<false><<<256, 512, 0, stream>>>(ws_att, ws_wp, proj_b, d_out,
                                                 32768, 512, 512);
}

// Round 4
// 266.593 us; speedup vs baseline: 1.1631x; 1.1631x over previous
//
#include <hip/hip_runtime.h>
#include <stdint.h>

typedef __attribute__((ext_vector_type(8))) __bf16 bf16x8;
typedef __attribute__((ext_vector_type(4))) float f32x4;
typedef __attribute__((ext_vector_type(4))) float fl4;
typedef __attribute__((ext_vector_type(8))) unsigned short us8;
typedef __attribute__((ext_vector_type(4))) unsigned short us4;

__device__ __forceinline__ unsigned short f2bf(float f) {
  union { float f; unsigned int u; } v;
  v.f = f;
  unsigned int r = v.u + 0x7FFFu + ((v.u >> 16) & 1u);
  return (unsigned short)(r >> 16);
}

#define GLOAD_LDS16(g, l)                                                   \
  __builtin_amdgcn_global_load_lds(                                         \
      (const __attribute__((address_space(1))) void*)(g),                   \
      (__attribute__((address_space(3))) void*)(l), 16, 0, 0)

// ---------------- fp32 -> bf16 conversion ----------------
__global__ void f32_to_bf16_kernel(const float* __restrict__ in,
                                   unsigned short* __restrict__ out, int n) {
  int i = (blockIdx.x * blockDim.x + threadIdx.x) * 4;
  if (i + 3 < n) {
    fl4 v = *(const fl4*)(in + i);
    us4 o;
    o[0] = f2bf(v[0]);
    o[1] = f2bf(v[1]);
    o[2] = f2bf(v[2]);
    o[3] = f2bf(v[3]);
    *(us4*)(out + i) = o;
  }
}

// ------- 128x128 4-wave double-buffered 2-phase bf16 NT GEMM ----
// C = A(MxK) * B(NxK)^T + bias. A,B row-major K-contiguous bf16.
// BM=BN=128, BK=64, 256 threads (2x2 waves), per-wave C = 64x64 (4x4 frags).
// LDS 64 KB: [2 buf][A 16KB + B 16KB], T2 swizzle byte ^= ((row&7)<<4)
// via inverse-swizzled global source (linear global_load_lds dest) +
// swizzled ds_read. Prefetch STAGE(kt+1) issued before compute of kt;
// ONE __syncthreads() per K-tile (drains vmcnt AND lgkmcnt -> prefetched
// tile landed + all LDS reads of the overwrite-target buffer complete;
// raw s_barrier w/o lgkmcnt drain raced under graph replay in R3).
template <bool OUT_BF16>
__global__ __launch_bounds__(256, 2) void gemm128_kernel(
    const unsigned short* __restrict__ A, const unsigned short* __restrict__ B,
    const float* __restrict__ bias, void* __restrict__ Cout, int M, int N,
    int K, int NT) {
  __shared__ __align__(16) unsigned short lds[32768];  // 64 KB
  char* base = (char*)lds;

  const int tid = threadIdx.x;
  const int lane = tid & 63;
  const int wid = tid >> 6;
  const int lr = lane & 15;
  const int lg = lane >> 4;
  const int wr = (wid >> 1) * 64;
  const int wc = (wid & 1) * 64;

  // supertile-32 mapping: 32 consecutive M-tiles x all NT N-tiles per super-row
  const int bid = blockIdx.x;
  const int bm = ((bid & 31) + (bid / (32 * NT)) * 32) << 7;
  const int bn = (((bid >> 5) % NT)) << 7;

  // staging: thread t covers rows srow+i*32, 16B col chunk (t&7)*16,
  // source col pre-swizzled so LDS[row][c'] = data[row][c' ^ ((row&7)<<4)]
  const int srow = tid >> 3;  // 0..31
  const int scolsw = ((tid & 7) << 4) ^ ((srow & 7) << 4);
  const char* Ag = (const char*)A;
  const char* Bg = (const char*)B;
  const size_t Kb = (size_t)K * 2;

#define STAGE(kt, p)                                                          \
  {                                                                           \
    char* la_ = base + (p) * 32768;                                           \
    char* lb_ = la_ + 16384;                                                  \
    _Pragma("unroll") for (int i_ = 0; i_ < 4; ++i_) {                        \
      GLOAD_LDS16(Ag + (size_t)(bm + srow + i_ * 32) * Kb + (kt) * 128 + scolsw, \
                  la_ + srow * 128 + i_ * 4096 + (tid & 7) * 16);             \
      GLOAD_LDS16(Bg + (size_t)(bn + srow + i_ * 32) * Kb + (kt) * 128 + scolsw, \
                  lb_ + srow * 128 + i_ * 4096 + (tid & 7) * 16);             \
    }                                                                         \
  }

  // swizzled ds_read col offsets
  const int swz = (lr & 7) << 4;
  const int ck0 = (lg << 4) ^ swz;         // kk=0
  const int ck1 = (64 + (lg << 4)) ^ swz;  // kk=1

  f32x4 acc[4][4];
#pragma unroll
  for (int m = 0; m < 4; ++m)
#pragma unroll
    for (int n = 0; n < 4; ++n) acc[m][n] = (f32x4){0.f, 0.f, 0.f, 0.f};

  const int nkt = K >> 6;

  STAGE(0, 0);
  __syncthreads();  // tile 0 landed (vmcnt drained)

  for (int kt = 0; kt < nkt; ++kt) {
    const int p = kt & 1;
    if (kt + 1 < nkt) STAGE(kt + 1, p ^ 1);  // prefetch overlaps compute

    const char* la = base + p * 32768;
    const char* lb = la + 16384;
    bf16x8 af[4][2], bfr[4][2];
#pragma unroll
    for (int m = 0; m < 4; ++m) {
      const int arow = (wr + m * 16 + lr) << 7;
      af[m][0] = *(const bf16x8*)(la + arow + ck0);
      af[m][1] = *(const bf16x8*)(la + arow + ck1);
    }
#pragma unroll
    for (int n = 0; n < 4; ++n) {
      const int brow = (wc + n * 16 + lr) << 7;
      bfr[n][0] = *(const bf16x8*)(lb + brow + ck0);
      bfr[n][1] = *(const bf16x8*)(lb + brow + ck1);
    }
#pragma unroll
    for (int kk = 0; kk < 2; ++kk)
#pragma unroll
      for (int m = 0; m < 4; ++m)
#pragma unroll
        for (int n = 0; n < 4; ++n)
          acc[m][n] = __builtin_amdgcn_mfma_f32_16x16x32_bf16(
              af[m][kk], bfr[n][kk], acc[m][n], 0, 0, 0);
    // drains vmcnt (next tile landed) AND lgkmcnt (this tile's ds_reads
    // complete -> safe for anyone to overwrite buffer p next iteration)
    __syncthreads();
  }
#undef STAGE

  // epilogue: C/D layout col = lane&15, row = lg*4 + j
  const int crow0 = bm + wr + lg * 4;
  const int ccol0 = bn + wc + lr;
#pragma unroll
  for (int n = 0; n < 4; ++n) {
    const int col = ccol0 + n * 16;
    const float bv = bias[col];
#pragma unroll
    for (int m = 0; m < 4; ++m) {
#pragma unroll
      for (int j = 0; j < 4; ++j) {
        const int row = crow0 + m * 16 + j;
        const float val = acc[m][n][j] + bv;
        if (OUT_BF16)
          ((unsigned short*)Cout)[(size_t)row * N + col] = f2bf(val);
        else
          ((float*)Cout)[(size_t)row * N + col] = val;
      }
    }
  }
}

// ---------------- attention: one WG (4 waves) per (b, h) ----------------
// In-register softmax on S fragments; XCD-chunked block remap.
__global__ __launch_bounds__(256, 4) void attn_kernel(
    const unsigned short* __restrict__ qkv, const float* __restrict__ abias,
    const float* __restrict__ mask, unsigned short* __restrict__ out) {
  __shared__ __align__(16) unsigned short lq[64 * 40];
  __shared__ __align__(16) unsigned short lk[64 * 40];
  __shared__ __align__(16) unsigned short lvT[32 * 72];
  __shared__ __align__(16) unsigned short lp[64 * 72];

  // XCD-chunked: all 16 heads of a window on the same XCD (shared qkv lines)
  const int bid = blockIdx.x;
  const int id2 = (bid & 7) * 1024 + (bid >> 3);
  const int b = id2 >> 4;
  const int h = id2 & 15;
  const int tid = threadIdx.x;
  const int lane = tid & 63;
  const int wid = tid >> 6;
  const int lr = lane & 15;
  const int lg = lane >> 4;
  const int lk8 = lg * 8;

  {
    const int r = tid >> 2;
    const int d0 = (tid & 3) * 8;
    const size_t bse = (size_t)(b * 64 + r) * 1536 + h * 32 + d0;
    us8 qv = *(const us8*)(qkv + bse);
    us8 kv = *(const us8*)(qkv + bse + 512);
    us8 vv = *(const us8*)(qkv + bse + 1024);
    *(us8*)(lq + r * 40 + d0) = qv;
    *(us8*)(lk + r * 40 + d0) = kv;
#pragma unroll
    for (int i = 0; i < 8; ++i) lvT[(d0 + i) * 72 + r] = vv[i];
  }
  __syncthreads();

  // S = q @ k^T (wave owns rows wid*16..+15), fused scale+bias+mask in-frag
  f32x4 s[4];
  {
    bf16x8 aq = *(const bf16x8*)(lq + (wid * 16 + lr) * 40 + lk8);
#pragma unroll
    for (int n = 0; n < 4; ++n) {
      bf16x8 bk = *(const bf16x8*)(lk + (n * 16 + lr) * 40 + lk8);
      f32x4 z = {0.f, 0.f, 0.f, 0.f};
      s[n] = __builtin_amdgcn_mfma_f32_16x16x32_bf16(aq, bk, z, 0, 0, 0);
    }
  }
  const float scale = 0.17677669529663687f;
  const int row0 = wid * 16 + lg * 4;  // + j
#pragma unroll
  for (int j = 0; j < 4; ++j) {
    const int row = row0 + j;
    const float* ab = abias + (h * 64 + row) * 64 + lr;
    const float* mk = mask + ((size_t)b * 64 + row) * 64 + lr;
#pragma unroll
    for (int n = 0; n < 4; ++n)
      s[n][j] = s[n][j] * scale + ab[n * 16] + mk[n * 16];
  }

  // in-register softmax per row j: reduce over n (in-reg) and lr (shfl 16-group)
  float mx[4], sm[4];
#pragma unroll
  for (int j = 0; j < 4; ++j)
    mx[j] = fmaxf(fmaxf(s[0][j], s[1][j]), fmaxf(s[2][j], s[3][j]));
#pragma unroll
  for (int xm = 1; xm <= 8; xm <<= 1)
#pragma unroll
    for (int j = 0; j < 4; ++j) mx[j] = fmaxf(mx[j], __shfl_xor(mx[j], xm));
#pragma unroll
  for (int j = 0; j < 4; ++j) sm[j] = 0.f;
#pragma unroll
  for (int n = 0; n < 4; ++n)
#pragma unroll
    for (int j = 0; j < 4; ++j) {
      const float e = __expf(s[n][j] - mx[j]);
      s[n][j] = e;
      sm[j] += e;
    }
#pragma unroll
  for (int xm = 1; xm <= 8; xm <<= 1)
#pragma unroll
    for (int j = 0; j < 4; ++j) sm[j] += __shfl_xor(sm[j], xm);
#pragma unroll
  for (int j = 0; j < 4; ++j) sm[j] = 1.f / sm[j];
#pragma unroll
  for (int n = 0; n < 4; ++n)
#pragma unroll
    for (int j = 0; j < 4; ++j)
      lp[(row0 + j) * 72 + n * 16 + lr] = f2bf(s[n][j] * sm[j]);
  __syncthreads();

  // O = P @ V
  f32x4 o[2];
  o[0] = (f32x4){0.f, 0.f, 0.f, 0.f};
  o[1] = o[0];
#pragma unroll
  for (int kk = 0; kk < 2; ++kk) {
    bf16x8 pa = *(const bf16x8*)(lp + (wid * 16 + lr) * 72 + kk * 32 + lk8);
#pragma unroll
    for (int d = 0; d < 2; ++d) {
      bf16x8 vb = *(const bf16x8*)(lvT + (d * 16 + lr) * 72 + kk * 32 + lk8);
      o[d] = __builtin_amdgcn_mfma_f32_16x16x32_bf16(pa, vb, o[d], 0, 0, 0);
    }
  }
#pragma unroll
  for (int d = 0; d < 2; ++d) {
    const int col = h * 32 + d * 16 + lr;
#pragma unroll
    for (int j = 0; j < 4; ++j) {
      const int row = row0 + j;
      out[(size_t)(b * 64 + row) * 512 + col] = f2bf(o[d][j]);
    }
  }
}

// ---------------- launch ----------------
extern "C" void kernel_launch(void* const* d_in, const int* in_sizes, int n_in,
                              void* d_out, int out_size, void* d_ws,
                              size_t ws_size, hipStream_t stream) {
  (void)in_sizes; (void)n_in; (void)out_size; (void)ws_size;
  const float* x = (const float*)d_in[0];
  const float* abias = (const float*)d_in[1];
  const float* mask = (const float*)d_in[2];
  const float* qkv_w = (const float*)d_in[3];
  const float* qkv_b = (const float*)d_in[4];
  const float* proj_w = (const float*)d_in[5];
  const float* proj_b = (const float*)d_in[6];

  char* ws = (char*)d_ws;
  unsigned short* ws_x = (unsigned short*)(ws);
  unsigned short* ws_qkv = (unsigned short*)(ws + 33554432);
  unsigned short* ws_wq = (unsigned short*)(ws + 134217728);
  unsigned short* ws_wp = (unsigned short*)(ws + 135790592);
  unsigned short* ws_att = ws_x;  // alias: x consumed by qkv GEMM before attn writes

  f32_to_bf16_kernel<<<16384, 256, 0, stream>>>(x, ws_x, 16777216);
  f32_to_bf16_kernel<<<768, 256, 0, stream>>>(qkv_w, ws_wq, 786432);
  f32_to_bf16_kernel<<<256, 256, 0, stream>>>(proj_w, ws_wp, 262144);

  // qkv: M=32768 (256 M-tiles), N=1536 (NT=12) -> 3072 blocks
  gemm128_kernel<true><<<3072, 256, 0, stream>>>(ws_x, ws_wq, qkv_b, ws_qkv,
                                                 32768, 1536, 512, 12);

  attn_kernel<<<8192, 256, 0, stream>>>(ws_qkv, abias, mask, ws_att);

  // proj: N=512 (NT=4) -> 1024 blocks
  gemm128_kernel<false><<<1024, 256, 0, stream>>>(ws_att, ws_wp, proj_b, d_out,
                                                  32768, 512, 512, 4);
}